// Round 10
// baseline (285.420 us; speedup 1.0000x reference)
//
#include <hip/hip_runtime.h>
#include <hip/hip_bf16.h>

// GraphConvNorm: scatter-mean by (row*7+edge_type) -> [N,896]@[896,128] -> BatchNorm.
// N=100000, C=128, E=700000. x/w/gamma/beta f32, indices auto int32/int64, out f32.
// Invariants: fused_k gather pinned ~102us (~2.1 TB/s random-line service) across
// r11-r16 -> machine ceiling. r16 showed edge bucketing itself is ~90-100us: 0.7M
// atomic RMWs on random lines of a 12.8MB meta array (> 4MB per-XCD L2) -> HBM
// latency per op. r17: CSR-ize so all atomic targets are L2-resident:
//   hist_k: cnt[r]++ (400KB, L2-hit) + pack_x/pack_w roles overlapped
//   alloc_k: chunked exclusive scan (block scan + atomic chunk reserve; order-free)
//   scat_k: pos=atomicAdd(basep[r]) (400KB) + 4B payload into dense 2.8MB ebuf
//   fused_k: start = basep[r]-cnt[r] (post-scatter basep = end); payload is
//            contiguous (1 line/node); no cap -> ovf_k DELETED; memset 12.8->0.4MB.
// fused_k phases 2 (MFMA) / epilogue (fused BN stats) unchanged from r15.
// ws: xbu 25.6MB + wp 0.23 + cnt 0.4 + basep 0.4 + ebuf 2.8 + stats 8KB + gctr.

typedef float  f32x4  __attribute__((ext_vector_type(4)));
typedef short  short8 __attribute__((ext_vector_type(8)));
typedef __bf16 bf16x8 __attribute__((ext_vector_type(8)));

union BFrag { uint4 q; short8 s; bf16x8 b; unsigned int u[4]; };

__device__ inline unsigned short f2bfbits(float f) {
    union { float f; unsigned int u; } v; v.f = f;
    unsigned int u = v.u;
    u += 0x7fffu + ((u >> 16) & 1u);   // RNE
    return (unsigned short)(u >> 16);
}
__device__ inline unsigned int pk_bf16(float lo, float hi) {
    float2 f; f.x = lo; f.y = hi;
    union { __hip_bfloat162 h; unsigned int u; } v;
    v.h = __float22bfloat162_rn(f);
    return v.u;
}
__device__ inline float bflo(unsigned int p) {
    union { unsigned int u; float f; } v; v.u = p << 16; return v.f;
}
__device__ inline float bfhi(unsigned int p) {
    union { unsigned int u; float f; } v; v.u = p & 0xffff0000u; return v.f;
}

#define LROW 452         // LDS row u32 (448 data + 4 pad)
#define TNODES 16
#define NPX 1024         // pack_x blocks inside hist_k

__device__ inline int idx_at(const int* __restrict__ p, int e, int mode) {
    return p[mode ? (e << 1) : e];
}
__device__ inline int detect_mode(const int* __restrict__ row, int tid) {
    const int li = tid & 63;
    int vodd = (li < 32) ? row[2 * li + 1] : 0;
    return __any(vodd != 0) ? 0 : 1;   // int64 -> high words all 0 -> mode 1
}

// ---- hist: cnt[r]++ per valid edge; pack_x / pack_w as extra block roles ----
__global__ __launch_bounds__(256) void hist_k(
    const float* __restrict__ x, const int* __restrict__ row,
    const int* __restrict__ col, const int* __restrict__ et,
    const float* __restrict__ w,
    unsigned int* __restrict__ xbu, short8* __restrict__ wp,
    unsigned int* __restrict__ cnt, int E, int N, int nEB)
{
    const int bid = blockIdx.x;
    const int tid = threadIdx.x;

    if (bid < nEB) {
        const int mode = detect_mode(row, tid);
        const int e = bid * 256 + tid;
        if (e < E) {
            int r = idx_at(row, e, mode);
            int c = idx_at(col, e, mode);
            int t = idx_at(et,  e, mode);
            if ((unsigned)r < (unsigned)N && (unsigned)c < (unsigned)N &&
                (unsigned)t < 6u)
                atomicAdd(&cnt[r], 1u);            // 400KB array: L2-hit atomics
        }
    } else if (bid < nEB + NPX) {
        const size_t total4 = (size_t)N * 32;
        for (size_t v = (size_t)(bid - nEB) * 256 + tid; v < total4;
             v += (size_t)NPX * 256) {
            f32x4 t = *(const f32x4*)(x + v * 4);
            xbu[v * 2]     = pk_bf16(t[0], t[1]);
            xbu[v * 2 + 1] = pk_bf16(t[2], t[3]);
        }
    } else {
        int u = (bid - nEB - NPX) * 256 + tid;
        if (u < 7 * 8 * 4 * 64) {
            int lane = u & 63, kc = (u >> 6) & 3, nt = (u >> 8) & 7, t = u >> 11;
            int quad = lane >> 4, lr = lane & 15;
            short8 s;
#pragma unroll
            for (int j = 0; j < 8; ++j)
                s[j] = (short)f2bfbits(
                    w[(size_t)(t * 128 + kc * 32 + quad * 8 + j) * 128
                      + nt * 16 + lr]);
            wp[u] = s;
        }
    }
}

// ---- alloc: exclusive base per node; chunk order irrelevant (disjointness) ----
__global__ __launch_bounds__(256) void alloc_k(const unsigned int* __restrict__ cnt,
                                               unsigned int* __restrict__ basep,
                                               unsigned int* __restrict__ gctr,
                                               int N)
{
    const int i = blockIdx.x * 256 + threadIdx.x;
    const int l = threadIdx.x & 63;
    const int wv = threadIdx.x >> 6;
    unsigned c = (i < N) ? cnt[i] : 0u;
    unsigned s = c;                                // wave inclusive scan
#pragma unroll
    for (int d = 1; d < 64; d <<= 1) {
        unsigned t = __shfl_up(s, d);
        if (l >= d) s += t;
    }
    __shared__ unsigned wt[4], wb[4];
    if (l == 63) wt[wv] = s;
    __syncthreads();
    if (threadIdx.x == 0) {
        unsigned tot = wt[0] + wt[1] + wt[2] + wt[3];
        unsigned gb  = atomicAdd(gctr, tot);       // reserve block chunk
        unsigned run = gb;
#pragma unroll
        for (int k = 0; k < 4; ++k) { wb[k] = run; run += wt[k]; }
    }
    __syncthreads();
    if (i < N) basep[i] = wb[wv] + s - c;          // exclusive base
}

// ---- scatter: payload (c<<3|t) into dense CSR; basep[r] becomes END ----
__global__ __launch_bounds__(256) void scat_k(
    const int* __restrict__ row, const int* __restrict__ col,
    const int* __restrict__ et, unsigned int* __restrict__ basep,
    int* __restrict__ ebuf, int E, int N)
{
    const int mode = detect_mode(row, threadIdx.x);
    const int e = blockIdx.x * 256 + threadIdx.x;
    if (e >= E) return;
    int r = idx_at(row, e, mode);
    int c = idx_at(col, e, mode);
    int t = idx_at(et,  e, mode);
    if ((unsigned)r < (unsigned)N && (unsigned)c < (unsigned)N && (unsigned)t < 6u) {
        unsigned pos = atomicAdd(&basep[r], 1u);   // L2-hit atomic
        ebuf[pos] = (c << 3) | t;                  // dense 2.8MB: L2-local write
    }
}

// ---- fused gather(xb)->means->LDS->GEMM(wp)->out + BN stats. ----
// 16 nodes/block, 8 waves (512 thr): 2 nodes/wave phase-1, 1 ntile/wave phase-2.
__global__ __launch_bounds__(512, 8) void fused_k(
    const unsigned int* __restrict__ cnt, const unsigned int* __restrict__ basep,
    const int* __restrict__ ebuf, const unsigned int* __restrict__ xbu,
    const uint4* __restrict__ wpq, float* __restrict__ out,
    float* __restrict__ statsR, int N)
{
    __shared__ unsigned int cold[TNODES * LROW];   // 28928 B; 4 blocks/CU (wave cap)
    const int tid  = threadIdx.x;
    const int l    = tid & 63;
    const int wv   = tid >> 6;                     // 0..7
    const int quad = l >> 4, lr = l & 15;
    const int tile = blockIdx.x * TNODES;
    const int node0 = tile + wv * 2;

    // ================= phase 1: per-node type-means (2 nodes/wave) =========
    // lanes 0..3: {cnt[n0], end[n0], cnt[n1], end[n1]}
    unsigned cb = 0;
    if (node0 < N) {
        int rr = node0 + (l >> 1);
        if (l < 4 && rr < N) cb = (l & 1) ? basep[rr] : cnt[rr];
    }
    unsigned nEa[2], sta[2], paya[2], selfa[2];
    nEa[0] = (unsigned)__builtin_amdgcn_readlane((int)cb, 0);
    sta[0] = (unsigned)__builtin_amdgcn_readlane((int)cb, 1) - nEa[0];
    nEa[1] = (unsigned)__builtin_amdgcn_readlane((int)cb, 2);
    sta[1] = (unsigned)__builtin_amdgcn_readlane((int)cb, 3) - nEa[1];
    // issue payload + self rows for both nodes up front (all in flight)
    paya[0] = paya[1] = 0u; selfa[0] = selfa[1] = 0u;
    if (node0 < N) {
        if (l < (int)min(nEa[0], 64u)) paya[0] = (unsigned)ebuf[sta[0] + l];
        selfa[0] = xbu[(size_t)node0 * 64 + l];
        if (node0 + 1 < N) {
            if (l < (int)min(nEa[1], 64u)) paya[1] = (unsigned)ebuf[sta[1] + l];
            selfa[1] = xbu[(size_t)(node0 + 1) * 64 + l];
        }
    }

#pragma unroll
    for (int i = 0; i < 2; ++i) {
        const int r = node0 + i;
        if (r < N) {
            const unsigned nEf  = nEa[i];                       // full count
            const int      nE   = __builtin_amdgcn_readfirstlane(
                                      (int)min(nEf, 64u));      // in-reg count
            const unsigned mcur = paya[i];
            const unsigned sv   = selfa[i];

            float acc[6][2];
#pragma unroll
            for (int t = 0; t < 6; ++t) { acc[t][0] = 0.f; acc[t][1] = 0.f; }

            // clamped batch-8 issue loop over the in-register payload
            unsigned q[8]; int pj[8];
            for (int k = 0; k < nE; k += 8) {
                const int rem = nE - k;
#pragma unroll
                for (int j = 0; j < 8; ++j) {
                    pj[j] = (int)__shfl(mcur, k + min(j, rem - 1));
                    q[j]  = xbu[(size_t)(pj[j] >> 3) * 64 + l];
                }
#pragma unroll
                for (int j = 0; j < 8; ++j) {
                    unsigned qq = (j < rem) ? q[j] : 0u;   // zeroed dup: adds 0
                    float lo = bflo(qq), hi = bfhi(qq);
                    switch (__builtin_amdgcn_readfirstlane(pj[j] & 7)) {
                        case 0: acc[0][0] += lo; acc[0][1] += hi; break;
                        case 1: acc[1][0] += lo; acc[1][1] += hi; break;
                        case 2: acc[2][0] += lo; acc[2][1] += hi; break;
                        case 3: acc[3][0] += lo; acc[3][1] += hi; break;
                        case 4: acc[4][0] += lo; acc[4][1] += hi; break;
                        default: acc[5][0] += lo; acc[5][1] += hi; break;
                    }
                }
            }

            // per-type counts: ballot over in-register payload lanes
            const bool inb = l < nE;
            int c0 = (int)__popcll(__ballot(inb && ((mcur & 7u) == 0u)));
            int c1 = (int)__popcll(__ballot(inb && ((mcur & 7u) == 1u)));
            int c2 = (int)__popcll(__ballot(inb && ((mcur & 7u) == 2u)));
            int c3 = (int)__popcll(__ballot(inb && ((mcur & 7u) == 3u)));
            int c4 = (int)__popcll(__ballot(inb && ((mcur & 7u) == 4u)));
            int c5 = (int)__popcll(__ballot(inb && ((mcur & 7u) == 5u)));

            // exact tail for degree > 64 (essentially never; serial, broadcast)
            for (unsigned k = 64u; k < nEf; ++k) {
                int p = ebuf[sta[i] + k];
                unsigned qv = xbu[(size_t)(p >> 3) * 64 + l];
                float lo = bflo(qv), hi = bfhi(qv);
                switch (__builtin_amdgcn_readfirstlane(p & 7)) {
                    case 0: acc[0][0] += lo; acc[0][1] += hi; ++c0; break;
                    case 1: acc[1][0] += lo; acc[1][1] += hi; ++c1; break;
                    case 2: acc[2][0] += lo; acc[2][1] += hi; ++c2; break;
                    case 3: acc[3][0] += lo; acc[3][1] += hi; ++c3; break;
                    case 4: acc[4][0] += lo; acc[4][1] += hi; ++c4; break;
                    default: acc[5][0] += lo; acc[5][1] += hi; ++c5; break;
                }
            }

            const float iv0 = 1.0f / (float)max(c0, 1);
            const float iv1 = 1.0f / (float)max(c1, 1);
            const float iv2 = 1.0f / (float)max(c2, 1);
            const float iv3 = 1.0f / (float)max(c3, 1);
            const float iv4 = 1.0f / (float)max(c4, 1);
            const float iv5 = 1.0f / (float)max(c5, 1);

            // means -> LDS (bf16 pairs); self slot (t=6) = xb row verbatim
            const int mrow = (wv * 2 + i) * LROW;
            cold[mrow + 0 * 64 + l] = pk_bf16(acc[0][0] * iv0, acc[0][1] * iv0);
            cold[mrow + 1 * 64 + l] = pk_bf16(acc[1][0] * iv1, acc[1][1] * iv1);
            cold[mrow + 2 * 64 + l] = pk_bf16(acc[2][0] * iv2, acc[2][1] * iv2);
            cold[mrow + 3 * 64 + l] = pk_bf16(acc[3][0] * iv3, acc[3][1] * iv3);
            cold[mrow + 4 * 64 + l] = pk_bf16(acc[4][0] * iv4, acc[4][1] * iv4);
            cold[mrow + 5 * 64 + l] = pk_bf16(acc[5][0] * iv5, acc[5][1] * iv5);
            cold[mrow + 6 * 64 + l] = sv;
        }
    }
    __syncthreads();

    // ======== phase 2: [16,896] @ [896,16] per wave, 2 indep MFMA chains ====
    f32x4 oa0 = (f32x4){0.f, 0.f, 0.f, 0.f};
    f32x4 oa1 = (f32x4){0.f, 0.f, 0.f, 0.f};
#pragma unroll
    for (int t = 0; t < 4; ++t)
#pragma unroll
        for (int kc = 0; kc < 4; ++kc) {
            BFrag a, b;
            const int ko = t * 64 + kc * 16 + quad * 4;
            a.q = *(const uint4*)&cold[lr * LROW + ko];
            b.q = wpq[(size_t)(((t * 8 + wv) * 4 + kc) * 64) + l];
            oa0 = __builtin_amdgcn_mfma_f32_16x16x32_bf16(a.b, b.b, oa0, 0, 0, 0);
        }
#pragma unroll
    for (int t = 4; t < 7; ++t)
#pragma unroll
        for (int kc = 0; kc < 4; ++kc) {
            BFrag a, b;
            const int ko = t * 64 + kc * 16 + quad * 4;
            a.q = *(const uint4*)&cold[lr * LROW + ko];
            b.q = wpq[(size_t)(((t * 8 + wv) * 4 + kc) * 64) + l];
            oa1 = __builtin_amdgcn_mfma_f32_16x16x32_bf16(a.b, b.b, oa1, 0, 0, 0);
        }
    // epilogue + fused BN stats. C/D: col=lr -> ch=wv*16+lr, row=quad*4+j -> node
    float s = 0.f, s2 = 0.f;
    const int ch = wv * 16 + lr;
#pragma unroll
    for (int j = 0; j < 4; ++j) {
        int m = tile + quad * 4 + j;
        if (m < N) {
            float v = oa0[j] + oa1[j];
            out[(size_t)m * 128 + ch] = v;
            s += v; s2 += v * v;
        }
    }
    s  += __shfl_xor(s, 16);  s  += __shfl_xor(s, 32);   // reduce across quads
    s2 += __shfl_xor(s2, 16); s2 += __shfl_xor(s2, 32);
    if (l < 16) {
        float* st = statsR + (size_t)(blockIdx.x & 7) * 256;   // 8 replicas
        atomicAdd(&st[ch],       s);
        atomicAdd(&st[128 + ch], s2);
    }
}

// ---- BN finalize: sums 8 stat replicas; coalesced vec4; no LDS ----
__global__ __launch_bounds__(256) void norm_k(
    float* __restrict__ out, const float* __restrict__ statsR,
    const float* __restrict__ gamma, const float* __restrict__ beta, int N)
{
    const int c0 = (threadIdx.x * 4) & 127;     // grid stride is mult. of 128 elems
    const float invN = 1.0f / (float)N;
    f32x4 sc, bi;
#pragma unroll
    for (int j = 0; j < 4; ++j) {
        int c = c0 + j;
        float sm = 0.f, sq = 0.f;
#pragma unroll
        for (int rep = 0; rep < 8; ++rep) {
            sm += statsR[rep * 256 + c];
            sq += statsR[rep * 256 + 128 + c];
        }
        float mean = sm * invN;
        float var  = sq * invN - mean * mean;
        float s = gamma[c] * rsqrtf(var + 1e-5f);
        sc[j] = s; bi[j] = beta[c] - mean * s;
    }
    const size_t nv = (size_t)N * 32;           // vec4 count
    for (size_t v = (size_t)blockIdx.x * 256 + threadIdx.x; v < nv;
         v += (size_t)gridDim.x * 256) {
        f32x4 x = *(f32x4*)(out + v * 4);
#pragma unroll
        for (int j = 0; j < 4; ++j) x[j] = x[j] * sc[j] + bi[j];
        *(f32x4*)(out + v * 4) = x;
    }
}

extern "C" void kernel_launch(void* const* d_in, const int* in_sizes, int n_in,
                              void* d_out, int out_size, void* d_ws, size_t ws_size,
                              hipStream_t stream)
{
    const float* x     = (const float*)d_in[0];
    const int*   row   = (const int*)d_in[1];
    const int*   col   = (const int*)d_in[2];
    const int*   etype = (const int*)d_in[3];
    const float* w     = (const float*)d_in[4];
    const float* gamma = (const float*)d_in[5];
    const float* beta  = (const float*)d_in[6];
    float* out = (float*)d_out;

    const int N = in_sizes[0] / 128;   // 100000
    const int E = in_sizes[1];         // 700000

    char* ws = (char*)d_ws;
    unsigned int* xbu   = (unsigned int*)ws;                              // N*64 u32
    short8*       wp    = (short8*)(ws + (size_t)N * 256);                // 229376 B
    unsigned int* cnt   = (unsigned int*)((char*)wp + 7 * 8 * 4 * 64 * 16); // N u32
    unsigned int* basep = cnt + N;                                        // N u32
    int*          ebuf  = (int*)(basep + N);                              // E int
    float*        stats = (float*)(ebuf + E);                             // 8*256 f32
    unsigned int* gctr  = (unsigned int*)(stats + 8 * 256);               // 1 u32

    hipMemsetAsync(cnt,   0, (size_t)N * 4,        stream);
    hipMemsetAsync(stats, 0, 8 * 256 * 4 + 8,      stream);   // covers gctr

    const int nEB = (E + 255) / 256;               // 2735 edge blocks
    const int nPW = (7 * 8 * 4 * 64 + 255) / 256;  // 56 pack_w blocks
    hist_k<<<nEB + NPX + nPW, 256, 0, stream>>>(x, row, col, etype, w,
                                                xbu, wp, cnt, E, N, nEB);
    alloc_k<<<(N + 255) / 256, 256, 0, stream>>>(cnt, basep, gctr, N);
    scat_k<<<nEB, 256, 0, stream>>>(row, col, etype, basep, ebuf, E, N);
    fused_k<<<(N + TNODES - 1) / TNODES, 512, 0, stream>>>(cnt, basep, ebuf, xbu,
                                                           (const uint4*)wp, out,
                                                           stats, N);
    norm_k<<<2048, 256, 0, stream>>>(out, stats, gamma, beta, N);
}

// Round 11
// 255.203 us; speedup vs baseline: 1.1184x; 1.1184x over previous
//
#include <hip/hip_runtime.h>
#include <hip/hip_bf16.h>

// GraphConvNorm: scatter-mean by (row*7+edge_type) -> [N,896]@[896,128] -> BatchNorm.
// N=100000, C=128, E=700000. x/w/gamma/beta f32, indices auto int32/int64, out f32.
// r18 = revert to r16 (best: 256.0us). r17's CSR experiment FALSIFIED the
// "L2-resident atomics are cheap" theory: gfx950 global atomics are device-scope,
// serviced at a coherence point independent of array size (8 non-coherent per-XCD
// L2s) -> hist/alloc/scat added passes for zero atomic savings, and fused_k's
// CSR metadata chain (cnt->base->ebuf->xbu) added one serialized latency per node
// pair (102->110us). Pinned ceilings (measured, invariant): fused gather ~102us
// (~2.1 TB/s random 256B-line service; occ 48-74% and 4 geometries all null),
// edge bucketing ~90us (0.7M device-scope RMWs at fabric atomic rate; 3 layouts
// null), norm ~17us (stream BW). Serial floor ~230us; r16 is within ~11%.
// Micro-cleanup vs r16: meta+ovfcnt contiguous -> single memset (one less launch).
// ws: xb 25.6MB + wp 0.23 + meta 12.8MB + ovfcnt 2.8MB + ovf 2.8MB + stats 8KB.

typedef float  f32x4  __attribute__((ext_vector_type(4)));
typedef short  short8 __attribute__((ext_vector_type(8)));
typedef __bf16 bf16x8 __attribute__((ext_vector_type(8)));

union BFrag { uint4 q; short8 s; bf16x8 b; unsigned int u[4]; };

__device__ inline unsigned short f2bfbits(float f) {
    union { float f; unsigned int u; } v; v.f = f;
    unsigned int u = v.u;
    u += 0x7fffu + ((u >> 16) & 1u);   // RNE
    return (unsigned short)(u >> 16);
}
__device__ inline unsigned int pk_bf16(float lo, float hi) {
    float2 f; f.x = lo; f.y = hi;
    union { __hip_bfloat162 h; unsigned int u; } v;
    v.h = __float22bfloat162_rn(f);
    return v.u;
}
__device__ inline float bflo(unsigned int p) {
    union { unsigned int u; float f; } v; v.u = p << 16; return v.f;
}
__device__ inline float bfhi(unsigned int p) {
    union { unsigned int u; float f; } v; v.u = p & 0xffff0000u; return v.f;
}

#define BUCKET_CAP 31
#define ROWW 32          // meta row: w0 = fill, w1-31 = payload  (one 128B line)
#define LROW 452         // LDS row u32 (448 data + 4 pad)
#define TNODES 16
#define NPX 1024         // pack_x blocks inside prep_k

__device__ inline int idx_at(const int* __restrict__ p, int e, int mode) {
    return p[mode ? (e << 1) : e];
}

// ---- prep: one kernel, three block roles (overlapped by the scheduler) ----
// [0, nEB)            : edge bucketing (atomic append into 128B meta rows)
// [nEB, nEB+NPX)      : pack_x  (x f32 -> xbu bf16-pair u32, grid-stride)
// [nEB+NPX, +56)      : pack_w  (W -> MFMA B-frag bf16 order)
__global__ __launch_bounds__(256) void prep_k(
    const float* __restrict__ x, const int* __restrict__ row,
    const int* __restrict__ col, const int* __restrict__ et,
    const float* __restrict__ w,
    unsigned int* __restrict__ xbu, short8* __restrict__ wp,
    unsigned int* __restrict__ meta, unsigned int* __restrict__ ovfcnt,
    int* __restrict__ ovf, int* __restrict__ novf,
    int E, int N, int nEB)
{
    const int bid = blockIdx.x;
    const int tid = threadIdx.x;

    if (bid < nEB) {
        // ---------------- edge role ----------------
        // index-width autodetect (per wave; all lanes participate in __any)
        const int li = tid & 63;
        int vodd = (li < 32) ? row[2 * li + 1] : 0;
        const int mode = __any(vodd != 0) ? 0 : 1;

        const int e = bid * 256 + tid;
        if (e < E) {
            int r = idx_at(row, e, mode);
            int c = idx_at(col, e, mode);
            int t = idx_at(et,  e, mode);
            if ((unsigned)r < (unsigned)N && (unsigned)c < (unsigned)N &&
                (unsigned)t < 6u) {
                unsigned pos = atomicAdd(&meta[(size_t)r * ROWW], 1u);
                if (pos < BUCKET_CAP) {
                    meta[(size_t)r * ROWW + 1 + pos] = (unsigned)((c << 3) | t);
                } else {                              // essentially never
                    atomicAdd(&ovfcnt[r * 7 + t], 1u);
                    ovf[atomicAdd(novf, 1)] = e;
                }
            }
        }
    } else if (bid < nEB + NPX) {
        // ---------------- pack_x role ----------------
        const size_t total4 = (size_t)N * 32;
        for (size_t v = (size_t)(bid - nEB) * 256 + tid; v < total4;
             v += (size_t)NPX * 256) {
            f32x4 t = *(const f32x4*)(x + v * 4);
            xbu[v * 2]     = pk_bf16(t[0], t[1]);
            xbu[v * 2 + 1] = pk_bf16(t[2], t[3]);
        }
    } else {
        // ---------------- pack_w role ----------------
        int u = (bid - nEB - NPX) * 256 + tid;
        if (u < 7 * 8 * 4 * 64) {
            int lane = u & 63, kc = (u >> 6) & 3, nt = (u >> 8) & 7, t = u >> 11;
            int quad = lane >> 4, lr = lane & 15;
            short8 s;
#pragma unroll
            for (int j = 0; j < 8; ++j)
                s[j] = (short)f2bfbits(
                    w[(size_t)(t * 128 + kc * 32 + quad * 8 + j) * 128
                      + nt * 16 + lr]);
            wp[u] = s;
        }
    }
}

// ---- fused gather(xb)->means->LDS->GEMM(wp)->out + BN stats. ----
// 16 nodes/block, 8 waves (512 thr): 2 nodes/wave phase-1, 1 ntile/wave phase-2.
__global__ __launch_bounds__(512, 8) void fused_k(
    const unsigned int* __restrict__ meta, const unsigned int* __restrict__ ovfcnt,
    const unsigned int* __restrict__ xbu, const uint4* __restrict__ wpq,
    float* __restrict__ out, float* __restrict__ statsR, int N)
{
    __shared__ unsigned int cold[TNODES * LROW];   // 28928 B; 4 blocks/CU (wave cap)
    const int tid  = threadIdx.x;
    const int l    = tid & 63;
    const int wv   = tid >> 6;                     // 0..7
    const int quad = l >> 4, lr = l & 15;
    const int tile = blockIdx.x * TNODES;
    const int base = tile + wv * 2;

    // ================= phase 1: per-node type-means (2 nodes/wave) =========
    unsigned mv = 0, self = 0;
    if (base < N) {
        mv   = (l < ROWW) ? meta[(size_t)base * ROWW + l] : 0u;
        self = xbu[(size_t)base * 64 + l];
    }
#pragma unroll
    for (int i = 0; i < 2; ++i) {
        const int r = base + i;
        if (r < N) {
            const unsigned fl = __shfl(mv, 0);
            const int nE = __builtin_amdgcn_readfirstlane(
                               (int)min(fl, (unsigned)BUCKET_CAP));
            const unsigned sv   = self;
            const unsigned mcur = mv;

            float acc[6][2];
#pragma unroll
            for (int t = 0; t < 6; ++t) { acc[t][0] = 0.f; acc[t][1] = 0.f; }

            // batch 0: 8 clamped loads, branch-free single clause -> all in flight
            unsigned q[8]; int pj[8];
            if (nE > 0) {
#pragma unroll
                for (int j = 0; j < 8; ++j) {
                    pj[j] = (int)__shfl(mcur, 1 + min(j, nE - 1));
                    q[j]  = xbu[(size_t)(pj[j] >> 3) * 64 + l];
                }
            }
            // prefetch next node metadata under the edge-load latency
            if (i == 0 && r + 1 < N) {
                mv   = (l < ROWW) ? meta[(size_t)(r + 1) * ROWW + l] : 0u;
                self = xbu[(size_t)(r + 1) * 64 + l];
            }
            if (nE > 0) {
#pragma unroll
                for (int j = 0; j < 8; ++j) {
                    unsigned qq = (j < nE) ? q[j] : 0u;   // zeroed dup: adds 0
                    float lo = bflo(qq), hi = bfhi(qq);
                    switch (__builtin_amdgcn_readfirstlane(pj[j] & 7)) {
                        case 0: acc[0][0] += lo; acc[0][1] += hi; break;
                        case 1: acc[1][0] += lo; acc[1][1] += hi; break;
                        case 2: acc[2][0] += lo; acc[2][1] += hi; break;
                        case 3: acc[3][0] += lo; acc[3][1] += hi; break;
                        case 4: acc[4][0] += lo; acc[4][1] += hi; break;
                        default: acc[5][0] += lo; acc[5][1] += hi; break;
                    }
                }
                // rare tail: degree > 8
                for (int k = 8; k < nE; k += 8) {
                    const int rem = nE - k;
#pragma unroll
                    for (int j = 0; j < 8; ++j) {
                        pj[j] = (int)__shfl(mcur, 1 + k + min(j, rem - 1));
                        q[j]  = xbu[(size_t)(pj[j] >> 3) * 64 + l];
                    }
#pragma unroll
                    for (int j = 0; j < 8; ++j) {
                        unsigned qq = (j < rem) ? q[j] : 0u;
                        float lo = bflo(qq), hi = bfhi(qq);
                        switch (__builtin_amdgcn_readfirstlane(pj[j] & 7)) {
                            case 0: acc[0][0] += lo; acc[0][1] += hi; break;
                            case 1: acc[1][0] += lo; acc[1][1] += hi; break;
                            case 2: acc[2][0] += lo; acc[2][1] += hi; break;
                            case 3: acc[3][0] += lo; acc[3][1] += hi; break;
                            case 4: acc[4][0] += lo; acc[4][1] += hi; break;
                            default: acc[5][0] += lo; acc[5][1] += hi; break;
                        }
                    }
                }
            }

            // per-type counts: ballot over in-bucket payload lanes 1..nE
            const bool inb = (l >= 1) && (l < 1 + nE);
            int c0 = (int)__popcll(__ballot(inb && ((mcur & 7u) == 0u)));
            int c1 = (int)__popcll(__ballot(inb && ((mcur & 7u) == 1u)));
            int c2 = (int)__popcll(__ballot(inb && ((mcur & 7u) == 2u)));
            int c3 = (int)__popcll(__ballot(inb && ((mcur & 7u) == 3u)));
            int c4 = (int)__popcll(__ballot(inb && ((mcur & 7u) == 4u)));
            int c5 = (int)__popcll(__ballot(inb && ((mcur & 7u) == 5u)));
            if (fl > (unsigned)BUCKET_CAP) {        // essentially never (cold)
                c0 += (int)ovfcnt[r * 7 + 0]; c1 += (int)ovfcnt[r * 7 + 1];
                c2 += (int)ovfcnt[r * 7 + 2]; c3 += (int)ovfcnt[r * 7 + 3];
                c4 += (int)ovfcnt[r * 7 + 4]; c5 += (int)ovfcnt[r * 7 + 5];
            }
            const float iv0 = 1.0f / (float)max(c0, 1);
            const float iv1 = 1.0f / (float)max(c1, 1);
            const float iv2 = 1.0f / (float)max(c2, 1);
            const float iv3 = 1.0f / (float)max(c3, 1);
            const float iv4 = 1.0f / (float)max(c4, 1);
            const float iv5 = 1.0f / (float)max(c5, 1);

            // means -> LDS (bf16 pairs); self slot (t=6) = xb row verbatim
            const int mrow = (wv * 2 + i) * LROW;
            cold[mrow + 0 * 64 + l] = pk_bf16(acc[0][0] * iv0, acc[0][1] * iv0);
            cold[mrow + 1 * 64 + l] = pk_bf16(acc[1][0] * iv1, acc[1][1] * iv1);
            cold[mrow + 2 * 64 + l] = pk_bf16(acc[2][0] * iv2, acc[2][1] * iv2);
            cold[mrow + 3 * 64 + l] = pk_bf16(acc[3][0] * iv3, acc[3][1] * iv3);
            cold[mrow + 4 * 64 + l] = pk_bf16(acc[4][0] * iv4, acc[4][1] * iv4);
            cold[mrow + 5 * 64 + l] = pk_bf16(acc[5][0] * iv5, acc[5][1] * iv5);
            cold[mrow + 6 * 64 + l] = sv;
        }
    }
    __syncthreads();

    // ======== phase 2: [16,896] @ [896,16] per wave, 2 indep MFMA chains ====
    f32x4 oa0 = (f32x4){0.f, 0.f, 0.f, 0.f};
    f32x4 oa1 = (f32x4){0.f, 0.f, 0.f, 0.f};
#pragma unroll
    for (int t = 0; t < 4; ++t)
#pragma unroll
        for (int kc = 0; kc < 4; ++kc) {
            BFrag a, b;
            const int ko = t * 64 + kc * 16 + quad * 4;
            a.q = *(const uint4*)&cold[lr * LROW + ko];
            b.q = wpq[(size_t)(((t * 8 + wv) * 4 + kc) * 64) + l];
            oa0 = __builtin_amdgcn_mfma_f32_16x16x32_bf16(a.b, b.b, oa0, 0, 0, 0);
        }
#pragma unroll
    for (int t = 4; t < 7; ++t)
#pragma unroll
        for (int kc = 0; kc < 4; ++kc) {
            BFrag a, b;
            const int ko = t * 64 + kc * 16 + quad * 4;
            a.q = *(const uint4*)&cold[lr * LROW + ko];
            b.q = wpq[(size_t)(((t * 8 + wv) * 4 + kc) * 64) + l];
            oa1 = __builtin_amdgcn_mfma_f32_16x16x32_bf16(a.b, b.b, oa1, 0, 0, 0);
        }
    // epilogue + fused BN stats. C/D: col=lr -> ch=wv*16+lr, row=quad*4+j -> node
    float s = 0.f, s2 = 0.f;
    const int ch = wv * 16 + lr;
#pragma unroll
    for (int j = 0; j < 4; ++j) {
        int m = tile + quad * 4 + j;
        if (m < N) {
            float v = oa0[j] + oa1[j];
            out[(size_t)m * 128 + ch] = v;
            s += v; s2 += v * v;
        }
    }
    s  += __shfl_xor(s, 16);  s  += __shfl_xor(s, 32);   // reduce across quads
    s2 += __shfl_xor(s2, 16); s2 += __shfl_xor(s2, 32);
    if (l < 16) {
        float* st = statsR + (size_t)(blockIdx.x & 7) * 256;   // 8 replicas
        atomicAdd(&st[ch],       s);
        atomicAdd(&st[128 + ch], s2);
    }
}

// ---- overflow repair: matvec xb[c]@W[t]/cnt -> out AND stats (replica 0) ----
__global__ void ovf_k(const int* __restrict__ ovf, const int* __restrict__ novf,
                      const int* __restrict__ row, const int* __restrict__ col,
                      const int* __restrict__ et,
                      const unsigned int* __restrict__ xbu,
                      const unsigned int* __restrict__ meta,
                      const unsigned int* __restrict__ ovfcnt,
                      const float* __restrict__ w,
                      float* __restrict__ out, float* __restrict__ statsR,
                      int nwaves)
{
    const int n = novf[0];
    if (n == 0) return;
    // index-width autodetect (inline; only reached when n > 0)
    int s = 0;
#pragma unroll
    for (int i = 1; i < 64; i += 2) s |= row[i];
    const int mode = (s == 0) ? 1 : 0;
    const int l = threadIdx.x & 63;
    for (int i = (blockIdx.x * 256 + threadIdx.x) >> 6; i < n; i += nwaves) {
        int e = ovf[i];
        int r = idx_at(row, e, mode);
        int c = idx_at(col, e, mode);
        int t = idx_at(et,  e, mode);
        // exact count = in-bucket ballot + overflow count word
        unsigned mv = (l < ROWW) ? meta[(size_t)r * ROWW + l] : 0u;
        unsigned fl = __shfl(mv, 0);
        int nE = (int)min(fl, (unsigned)BUCKET_CAP);
        bool inb = (l >= 1) && (l < 1 + nE);
        int ct = (int)__popcll(__ballot(inb && ((int)(mv & 7u) == t)))
               + (int)ovfcnt[r * 7 + t];
        float inv = 1.0f / (float)max(ct, 1);
        float d0 = 0.f, d1 = 0.f;
        for (int k = 0; k < 64; ++k) {
            unsigned xv = xbu[(size_t)c * 64 + k];
            float xlo = bflo(xv), xhi = bfhi(xv);
            const float* wr = w + (size_t)(t * 128 + 2 * k) * 128;
            d0 += xlo * wr[2 * l]     + xhi * wr[128 + 2 * l];
            d1 += xlo * wr[2 * l + 1] + xhi * wr[128 + 2 * l + 1];
        }
        d0 *= inv; d1 *= inv;
        float olo = atomicAdd(&out[(size_t)r * 128 + 2 * l],     d0);
        float ohi = atomicAdd(&out[(size_t)r * 128 + 2 * l + 1], d1);
        atomicAdd(&statsR[2 * l],           d0);
        atomicAdd(&statsR[128 + 2 * l],     d0 * (2.f * olo + d0));
        atomicAdd(&statsR[2 * l + 1],       d1);
        atomicAdd(&statsR[128 + 2 * l + 1], d1 * (2.f * ohi + d1));
    }
}

// ---- BN finalize: sums 8 stat replicas; coalesced vec4; no LDS ----
__global__ __launch_bounds__(256) void norm_k(
    float* __restrict__ out, const float* __restrict__ statsR,
    const float* __restrict__ gamma, const float* __restrict__ beta, int N)
{
    const int c0 = (threadIdx.x * 4) & 127;     // grid stride is mult. of 128 elems
    const float invN = 1.0f / (float)N;
    f32x4 sc, bi;
#pragma unroll
    for (int j = 0; j < 4; ++j) {
        int c = c0 + j;
        float sm = 0.f, sq = 0.f;
#pragma unroll
        for (int rep = 0; rep < 8; ++rep) {
            sm += statsR[rep * 256 + c];
            sq += statsR[rep * 256 + 128 + c];
        }
        float mean = sm * invN;
        float var  = sq * invN - mean * mean;
        float s = gamma[c] * rsqrtf(var + 1e-5f);
        sc[j] = s; bi[j] = beta[c] - mean * s;
    }
    const size_t nv = (size_t)N * 32;           // vec4 count
    for (size_t v = (size_t)blockIdx.x * 256 + threadIdx.x; v < nv;
         v += (size_t)gridDim.x * 256) {
        f32x4 x = *(f32x4*)(out + v * 4);
#pragma unroll
        for (int j = 0; j < 4; ++j) x[j] = x[j] * sc[j] + bi[j];
        *(f32x4*)(out + v * 4) = x;
    }
}

extern "C" void kernel_launch(void* const* d_in, const int* in_sizes, int n_in,
                              void* d_out, int out_size, void* d_ws, size_t ws_size,
                              hipStream_t stream)
{
    const float* x     = (const float*)d_in[0];
    const int*   row   = (const int*)d_in[1];
    const int*   col   = (const int*)d_in[2];
    const int*   etype = (const int*)d_in[3];
    const float* w     = (const float*)d_in[4];
    const float* gamma = (const float*)d_in[5];
    const float* beta  = (const float*)d_in[6];
    float* out = (float*)d_out;

    const int N = in_sizes[0] / 128;   // 100000
    const int E = in_sizes[1];         // 700000

    char* ws = (char*)d_ws;
    unsigned int* xbu    = (unsigned int*)ws;                             // N*64 u32
    short8*       wp     = (short8*)(ws + (size_t)N * 256);               // 229376 B
    unsigned int* meta   = (unsigned int*)((char*)wp + 7 * 8 * 4 * 64 * 16); // N*32 u32
    unsigned int* ovfcnt = (unsigned int*)((char*)meta + (size_t)N * ROWW * 4); // 7N u32
    int*          ovf    = (int*)((char*)ovfcnt + (size_t)N * 7 * 4);     // E int
    float*        stats  = (float*)((char*)ovf + (size_t)E * 4);          // 8*256 f32
    int*          novf   = (int*)((char*)stats + 8 * 256 * 4);            // 1 int

    // meta and ovfcnt are contiguous -> one memset covers both
    hipMemsetAsync(meta,  0, (size_t)N * (ROWW + 7) * 4, stream);
    hipMemsetAsync(stats, 0, 8 * 256 * 4 + 8,            stream);

    const int nEB = (E + 255) / 256;             // edge blocks (longest pole first)
    const int nPW = (7 * 8 * 4 * 64 + 255) / 256; // 56 pack_w blocks
    prep_k<<<nEB + NPX + nPW, 256, 0, stream>>>(x, row, col, etype, w,
                                                xbu, wp, meta, ovfcnt,
                                                ovf, novf, E, N, nEB);
    fused_k<<<(N + TNODES - 1) / TNODES, 512, 0, stream>>>(meta, ovfcnt, xbu,
                                                           (const uint4*)wp, out,
                                                           stats, N);
    ovf_k<<<64, 256, 0, stream>>>(ovf, novf, row, col, etype,
                                  xbu, meta, ovfcnt, w, out, stats, 256);
    norm_k<<<2048, 256, 0, stream>>>(out, stats, gamma, beta, N);
}